// Round 9
// baseline (133.964 us; speedup 1.0000x reference)
//
#include <hip/hip_runtime.h>
#include <hip/hip_bf16.h>
#include <math.h>

#define TOK 4096
#define CDIM 512
#define NHEADS 8
#define DH 64
#define NBH 16
#define NSEQ 2048
#define SQRT_C 22.62741699796952f
#define ATTN_SCALE 0.125f

typedef unsigned short ushort_t;
typedef __attribute__((ext_vector_type(8))) short short8;
typedef __attribute__((ext_vector_type(4))) short short4v;
typedef __attribute__((ext_vector_type(16))) float f32x16;
typedef __attribute__((ext_vector_type(4))) float f32x4;

__device__ inline ushort_t f2b(float f) {
  __hip_bfloat16 h = __float2bfloat16(f);
  return *(ushort_t*)&h;
}
__device__ inline f32x16 fzero16() {
  f32x16 v;
#pragma unroll
  for (int i = 0; i < 16; ++i) v[i] = 0.0f;
  return v;
}

__device__ inline void gload16(const ushort_t* g, ushort_t* l) {
  __builtin_amdgcn_global_load_lds(
      (const __attribute__((address_space(1))) unsigned int*)g,
      (__attribute__((address_space(3))) unsigned int*)l, 16, 0, 0);
}

// ---------------------------------------------------------------------------
// prep: fused W_qkv/W_proj row-normalize + x bf16 copy + x inv-norm.
// One wave per row; branch is block-uniform. Grid 8192.
// ---------------------------------------------------------------------------
__global__ __launch_bounds__(64) void prep_kernel(
    const float* __restrict__ W_qkv, const float* __restrict__ W_proj,
    const float* __restrict__ x,
    ushort_t* __restrict__ Wqn, ushort_t* __restrict__ Wpn,
    ushort_t* __restrict__ xb, float* __restrict__ xs) {
  const int bid = blockIdx.x;
  const float* src;
  ushort_t* dst;
  int row;
  bool isx = false;
  if (bid < 3072)      { src = W_qkv;  dst = Wqn; row = bid; }
  else if (bid < 4096) { src = W_proj; dst = Wpn; row = bid - 3072; }
  else                 { src = x;      dst = xb;  row = bid - 4096; isx = true; }

  const float4* p = (const float4*)(src + (size_t)row * CDIM);
  int t = threadIdx.x;
  float4 a = p[t];
  float4 b = p[t + 64];
  float s = a.x * a.x + a.y * a.y + a.z * a.z + a.w * a.w
          + b.x * b.x + b.y * b.y + b.z * b.z + b.w * b.w;
#pragma unroll
  for (int off = 32; off > 0; off >>= 1) s += __shfl_down(s, off);
  s = __shfl(s, 0);
  float inv;
  if (isx) {
    if (t == 0) xs[row] = 1.0f / (sqrtf(s) * SQRT_C);
    inv = 1.0f;
  } else {
    inv = 1.0f / sqrtf(s);
  }
  short4v ya, yb;
  ya[0] = (short)f2b(a.x * inv); ya[1] = (short)f2b(a.y * inv);
  ya[2] = (short)f2b(a.z * inv); ya[3] = (short)f2b(a.w * inv);
  yb[0] = (short)f2b(b.x * inv); yb[1] = (short)f2b(b.y * inv);
  yb[2] = (short)f2b(b.z * inv); yb[3] = (short)f2b(b.w * inv);
  *(short4v*)&dst[(size_t)row * CDIM + t * 4] = ya;
  *(short4v*)&dst[(size_t)row * CDIM + 256 + t * 4] = yb;
}

// ---------------------------------------------------------------------------
// bcos GEMM, bf16 MFMA 16x16x32. 128m x (NJ*16)ch tile (NJ*32 W rows, pair
// halves interleaved in 16-row groups). BK=64 as two BK=32 sub-stages.
// 4 waves: mq=w&1 (64 m), wq=w>>1.
// MODE 0 (NJ=4): Qb [bh][n][64] (x0.125), Kt/Vt [bh][d][n]; ascale = x invnorm.
// MODE 1 (NJ=2): fp32 out; osum_p[8][4096] summed in LDS, rsqrt in epilogue.
// ---------------------------------------------------------------------------
template <int MODE, int NJ>
__global__ __launch_bounds__(256) void gemm_mfma_kernel(
    const ushort_t* __restrict__ Ab,
    const ushort_t* __restrict__ Wn,
    const float* __restrict__ ascale,
    const float* __restrict__ osum_p,
    float* __restrict__ out,
    ushort_t* __restrict__ Qb, ushort_t* __restrict__ Ktb,
    ushort_t* __restrict__ Vtb,
    int P) {
  __shared__ __align__(16) ushort_t At[2][128 * 32];
  __shared__ __align__(16) ushort_t Wt[2][NJ * 32 * 32];
  __shared__ float osl[128];
  const int t = threadIdx.x;
  const int lane = t & 63;
  const int w = t >> 6;
  const int mq = w & 1, wq = w >> 1;
  const int l15 = lane & 15, l4 = lane >> 4;
  const int n0 = blockIdx.x * (NJ * 16);
  const int mb = blockIdx.y * 128;

  if (MODE == 1) {
    if (t < 128) {
      float s = 0.f;
#pragma unroll
      for (int hh = 0; hh < 8; ++hh) s += osum_p[hh * TOK + mb + t];
      osl[t] = s;
    }
  }

  const int srow = lane >> 2;
  const int sch = (lane & 3) * 8;
  const int WI = NJ / 2;
  const ushort_t* ag[2];
  const ushort_t* wg[WI];
  ushort_t* al[2];
  ushort_t* wl[WI];
#pragma unroll
  for (int i = 0; i < 2; ++i) {
    int r = w * 32 + i * 16;
    ag[i] = Ab + (size_t)(mb + r + srow) * CDIM + sch;
    al[i] = &At[0][r * 32];
  }
#pragma unroll
  for (int i = 0; i < WI; ++i) {
    int r = w * (WI * 16) + i * 16;
    int g = r >> 4;
    int grow = n0 + (g >> 1) * 16 + srow + (g & 1) * P;
    wg[i] = Wn + (size_t)grow * CDIM + sch;
    wl[i] = &Wt[0][r * 32];
  }

  f32x4 acc[4][NJ];
#pragma unroll
  for (int i = 0; i < 4; ++i)
#pragma unroll
    for (int j = 0; j < NJ; ++j) acc[i][j] = (f32x4){0.f, 0.f, 0.f, 0.f};

  for (int it = 0; it < 8; ++it) {
    __syncthreads();
#pragma unroll
    for (int h = 0; h < 2; ++h) {
#pragma unroll
      for (int i = 0; i < 2; ++i) gload16(ag[i] + h * 32, al[i] + h * (128 * 32));
#pragma unroll
      for (int i = 0; i < WI; ++i) gload16(wg[i] + h * 32, wl[i] + h * (NJ * 32 * 32));
    }
#pragma unroll
    for (int i = 0; i < 2; ++i) ag[i] += 64;
#pragma unroll
    for (int i = 0; i < WI; ++i) wg[i] += 64;
    __syncthreads();
#pragma unroll
    for (int h = 0; h < 2; ++h) {
      short8 af[4], wf[NJ];
#pragma unroll
      for (int i = 0; i < 4; ++i)
        af[i] = *(const short8*)(&At[h][(mq * 64 + i * 16 + l15) * 32 + l4 * 8]);
#pragma unroll
      for (int j = 0; j < NJ; ++j)
        wf[j] = *(const short8*)(&Wt[h][(wq * (NJ * 16) + j * 16 + l15) * 32 + l4 * 8]);
#pragma unroll
      for (int i = 0; i < 4; ++i)
#pragma unroll
        for (int j = 0; j < NJ; ++j)
          acc[i][j] = __builtin_amdgcn_mfma_f32_16x16x32_bf16(af[i], wf[j], acc[i][j], 0, 0, 0);
    }
  }

  if (MODE == 0) {
    const int which = n0 >> 9;           // block-uniform (NJ=4 -> 64-ch tiles)
    const int h = (n0 & 511) >> 6;
    const int b = mb >> 11;
    const int bh = b * NHEADS + h;
    const int nsb = mb & 2047;
#pragma unroll
    for (int i = 0; i < 4; ++i) {
      const int ml = mq * 64 + i * 16 + l4 * 4;
      const float4 asc = *(const float4*)&ascale[mb + ml];
      const float ascv[4] = {asc.x, asc.y, asc.z, asc.w};
#pragma unroll
      for (int jt = 0; jt < NJ / 2; ++jt) {
        const int dh = (wq * (NJ / 2) + jt) * 16 + l15;
        f32x4 a0 = acc[i][2 * jt], a1 = acc[i][2 * jt + 1];
        if (which == 0) {
#pragma unroll
          for (int r = 0; r < 4; ++r) {
            float v = fmaxf(a0[r], a1[r]);
            Qb[((size_t)bh * NSEQ + nsb + ml + r) * DH + dh] =
                f2b(v * fabsf(v) * ascv[r] * ATTN_SCALE);
          }
        } else {
          ushort_t* dst = (which == 1) ? Ktb : Vtb;
          short4v pv;
#pragma unroll
          for (int r = 0; r < 4; ++r) {
            float v = fmaxf(a0[r], a1[r]);
            pv[r] = (short)f2b(v * fabsf(v) * ascv[r]);
          }
          *(short4v*)&dst[((size_t)bh * DH + dh) * NSEQ + nsb + ml] = pv;
        }
      }
    }
  } else {
#pragma unroll
    for (int i = 0; i < 4; ++i) {
      const int ml = mq * 64 + i * 16 + l4 * 4;
      const int m = mb + ml;
      float ascv[4];
#pragma unroll
      for (int r = 0; r < 4; ++r) ascv[r] = 1.0f / (sqrtf(osl[ml + r]) * SQRT_C);
#pragma unroll
      for (int jt = 0; jt < NJ / 2; ++jt) {
        const int c = n0 + (wq * (NJ / 2) + jt) * 16 + l15;
        f32x4 a0 = acc[i][2 * jt], a1 = acc[i][2 * jt + 1];
#pragma unroll
        for (int r = 0; r < 4; ++r) {
          float v = fmaxf(a0[r], a1[r]);
          out[(size_t)(m + r) * CDIM + c] = v * fabsf(v) * ascv[r];
        }
      }
    }
  }
}

// ---------------------------------------------------------------------------
// kvstat v3: one block per bh (grid 16). Each wave sweeps 512 keys. Staged
// LDS reduce (waves 0,1 store / 2,3 add), final summed store — no atomics,
// no partials. Ag[bh][66*64]: rows 0..63 M^T[dh][d], 64 ksum[d], 65 vsum[dh].
// ---------------------------------------------------------------------------
__global__ __launch_bounds__(256) void kvstat_kernel(
    const ushort_t* __restrict__ Ktb,
    const ushort_t* __restrict__ Vtb,
    float* __restrict__ Ag) {
  __shared__ float Lr[2 * 66 * 66];
  const int t = threadIdx.x;
  const int lane = t & 63;
  const int w = t >> 6;
  const int l31 = lane & 31;
  const int H = lane >> 5;
  const int bh = blockIdx.x;

  short8 onesf;
  {
    short v = (l31 == 0) ? (short)0x3F80 : (short)0;
#pragma unroll
    for (int i = 0; i < 8; ++i) onesf[i] = v;
  }

  f32x16 acc[3][3];
#pragma unroll
  for (int mt = 0; mt < 3; ++mt)
#pragma unroll
    for (int nt = 0; nt < 3; ++nt) acc[mt][nt] = fzero16();

  const ushort_t* Kbase = Ktb + (size_t)bh * DH * NSEQ + w * 512;
  const ushort_t* Vbase = Vtb + (size_t)bh * DH * NSEQ + w * 512;
#pragma unroll 4
  for (int c = 0; c < 32; ++c) {
    const int key = c * 16 + H * 8;
    short8 kf[2], vf[2];
#pragma unroll
    for (int mt = 0; mt < 2; ++mt) {
      kf[mt] = *(const short8*)(Kbase + (size_t)(mt * 32 + l31) * NSEQ + key);
      vf[mt] = *(const short8*)(Vbase + (size_t)(mt * 32 + l31) * NSEQ + key);
    }
#pragma unroll
    for (int mt = 0; mt < 3; ++mt) {
      short8 a = (mt < 2) ? kf[mt] : onesf;
#pragma unroll
      for (int nt = 0; nt < 3; ++nt) {
        if (mt == 2 && nt == 2) continue;
        short8 bfr = (nt < 2) ? vf[nt] : onesf;
        acc[mt][nt] = __builtin_amdgcn_mfma_f32_32x32x16_bf16(a, bfr, acc[mt][nt], 0, 0, 0);
      }
    }
  }

  float* D = Lr + (w & 1) * (66 * 66);
  if (w < 2) {
#pragma unroll
    for (int mt = 0; mt < 3; ++mt)
#pragma unroll
      for (int nt = 0; nt < 3; ++nt) {
        if (mt == 2 && nt == 2) continue;
#pragma unroll
        for (int r = 0; r < 16; ++r) {
          int rloc = (r & 3) + 8 * (r >> 2) + 4 * H;
          int row = (mt < 2) ? mt * 32 + rloc : 64;
          int col = (nt < 2) ? nt * 32 + l31 : 64;
          bool valid = (mt < 2 || rloc == 0) && (nt < 2 || l31 == 0);
          if (valid) D[row * 66 + col] = acc[mt][nt][r];
        }
      }
  }
  __syncthreads();
  if (w >= 2) {
#pragma unroll
    for (int mt = 0; mt < 3; ++mt)
#pragma unroll
      for (int nt = 0; nt < 3; ++nt) {
        if (mt == 2 && nt == 2) continue;
#pragma unroll
        for (int r = 0; r < 16; ++r) {
          int rloc = (r & 3) + 8 * (r >> 2) + 4 * H;
          int row = (mt < 2) ? mt * 32 + rloc : 64;
          int col = (nt < 2) ? nt * 32 + l31 : 64;
          bool valid = (mt < 2 || rloc == 0) && (nt < 2 || l31 == 0);
          if (valid) D[row * 66 + col] += acc[mt][nt][r];
        }
      }
  }
  __syncthreads();

  float* ag = Ag + (size_t)bh * (66 * 64);
  const float* L0 = Lr;
  const float* L1 = Lr + 66 * 66;
  for (int e = t; e < 66 * 64; e += 256) {
    int j = e >> 6, i = e & 63;
    int idx = (j < 64) ? i * 66 + j : (j == 64 ? i * 66 + 64 : 64 * 66 + i);
    ag[e] = L0[idx] + L1[idx];
  }
}

// ---------------------------------------------------------------------------
// attn_apply: attn = (vsum + q~.M)/(2048 + q~.ksum). Reads final Ag.
// Writes bf16 attn + per-head osum partials (non-atomic).
// ---------------------------------------------------------------------------
__global__ __launch_bounds__(256) void attn_apply_kernel(
    const ushort_t* __restrict__ Qb,
    const float* __restrict__ Ag,
    ushort_t* __restrict__ attnb,
    float* __restrict__ osum_p) {      // [8][4096]
  __shared__ ushort_t Bs[96 * 72];
  __shared__ float vs_lds[64];
  const int t = threadIdx.x;
  const int lane = t & 63;
  const int w = t >> 6;
  const int l31 = lane & 31;
  const int H = lane >> 5;
  const int bh = blockIdx.y;
  const int tok0 = blockIdx.x * 128 + w * 32;

  const float* ag = Ag + (size_t)bh * (66 * 64);
  for (int e = t; e < 64 * 64; e += 256)
    Bs[(e >> 6) * 72 + (e & 63)] = f2b(ag[e]);
  for (int e = t; e < 32 * 64; e += 256) {
    int j = e >> 6, i = e & 63;
    Bs[(64 + j) * 72 + i] = (j == 0) ? f2b(ag[64 * 64 + i]) : 0;
  }
  if (t < 64) vs_lds[t] = ag[65 * 64 + t];
  __syncthreads();

  short8 qf[4];
  {
    const ushort_t* qp = Qb + ((size_t)bh * NSEQ + tok0 + l31) * DH + H * 8;
#pragma unroll
    for (int c = 0; c < 4; ++c) qf[c] = *(const short8*)(qp + c * 16);
  }

  f32x16 oacc[3];
#pragma unroll
  for (int nt = 0; nt < 3; ++nt) oacc[nt] = fzero16();
#pragma unroll
  for (int c = 0; c < 4; ++c) {
#pragma unroll
    for (int nt = 0; nt < 3; ++nt) {
      short8 bfr = *(const short8*)(Bs + (nt * 32 + l31) * 72 + c * 16 + H * 8);
      oacc[nt] = __builtin_amdgcn_mfma_f32_32x32x16_bf16(qf[c], bfr, oacc[nt], 0, 0, 0);
    }
  }

  const int b = bh >> 3, h = bh & 7;
#pragma unroll
  for (int r = 0; r < 16; ++r) {
    int rloc = (r & 3) + 8 * (r >> 2) + 4 * H;
    float den = 2048.0f + __shfl(oacc[2][r], H * 32);
    float inv = 1.0f / den;
    float v0 = (vs_lds[l31] + oacc[0][r]) * inv;
    float v1 = (vs_lds[32 + l31] + oacc[1][r]) * inv;
    int n = tok0 + rloc;
    ushort_t* op = attnb + ((size_t)(b * NSEQ + n)) * CDIM + h * DH;
    op[l31] = f2b(v0);
    op[32 + l31] = f2b(v1);
    float ss = v0 * v0 + v1 * v1;
#pragma unroll
    for (int off = 16; off > 0; off >>= 1) ss += __shfl_down(ss, off, 32);
    if (l31 == 0) osum_p[h * TOK + b * NSEQ + n] = ss;
  }
}

extern "C" void kernel_launch(void* const* d_in, const int* in_sizes, int n_in,
                              void* d_out, int out_size, void* d_ws, size_t ws_size,
                              hipStream_t stream) {
  const float* x      = (const float*)d_in[0];
  const float* W_qkv  = (const float*)d_in[1];
  const float* W_proj = (const float*)d_in[2];
  float* out = (float*)d_out;

  char* wsb = (char*)d_ws;
  ushort_t* Wqn = (ushort_t*)(wsb + 0);          // 3072x512 bf16
  ushort_t* Wpn = (ushort_t*)(wsb + 3145728);    // 1024x512 bf16
  ushort_t* xb  = (ushort_t*)(wsb + 4194304);    // 4096x512 bf16; reused as attnb
  ushort_t* Qb  = (ushort_t*)(wsb + 8388608);    // [bh][n][64] bf16
  ushort_t* Ktb = (ushort_t*)(wsb + 12582912);   // [bh][d][n] bf16
  ushort_t* Vtb = (ushort_t*)(wsb + 16777216);   // [bh][dh][n] bf16
  float* xs     = (float*)(wsb + 20971520);      // 4096
  float* osum_p = (float*)(wsb + 20987904);      // 8 x 4096
  float* Ag     = (float*)(wsb + 21118976);      // 16 x 66*64

  prep_kernel<<<8192, 64, 0, stream>>>(W_qkv, W_proj, x, Wqn, Wpn, xb, xs);

  gemm_mfma_kernel<0, 4><<<dim3(1536 / 64, TOK / 128), 256, 0, stream>>>(
      xb, Wqn, xs, nullptr, nullptr, Qb, Ktb, Vtb, 1536);

  kvstat_kernel<<<NBH, 256, 0, stream>>>(Ktb, Vtb, Ag);

  attn_apply_kernel<<<dim3(16, NBH), 256, 0, stream>>>(Qb, Ag, xb, osum_p);

  gemm_mfma_kernel<1, 2><<<dim3(512 / 32, TOK / 128), 256, 0, stream>>>(
      xb, Wpn, nullptr, osum_p, out, nullptr, nullptr, nullptr, 512);
}

// Round 10
// 122.432 us; speedup vs baseline: 1.0942x; 1.0942x over previous
//
#include <hip/hip_runtime.h>
#include <hip/hip_bf16.h>
#include <math.h>

#define TOK 4096
#define CDIM 512
#define NHEADS 8
#define DH 64
#define NBH 16
#define NSEQ 2048
#define SQRT_C 22.62741699796952f
#define ATTN_SCALE 0.125f

typedef unsigned short ushort_t;
typedef __attribute__((ext_vector_type(8))) short short8;
typedef __attribute__((ext_vector_type(4))) short short4v;
typedef __attribute__((ext_vector_type(16))) float f32x16;
typedef __attribute__((ext_vector_type(4))) float f32x4;

__device__ inline ushort_t f2b(float f) {
  __hip_bfloat16 h = __float2bfloat16(f);
  return *(ushort_t*)&h;
}
__device__ inline f32x16 fzero16() {
  f32x16 v;
#pragma unroll
  for (int i = 0; i < 16; ++i) v[i] = 0.0f;
  return v;
}

__device__ inline void gload16(const ushort_t* g, ushort_t* l) {
  __builtin_amdgcn_global_load_lds(
      (const __attribute__((address_space(1))) unsigned int*)g,
      (__attribute__((address_space(3))) unsigned int*)l, 16, 0, 0);
}

// ---------------------------------------------------------------------------
// prep: fused W_qkv/W_proj row-normalize + x bf16 copy + x inv-norm.
// ---------------------------------------------------------------------------
__global__ __launch_bounds__(64) void prep_kernel(
    const float* __restrict__ W_qkv, const float* __restrict__ W_proj,
    const float* __restrict__ x,
    ushort_t* __restrict__ Wqn, ushort_t* __restrict__ Wpn,
    ushort_t* __restrict__ xb, float* __restrict__ xs) {
  const int bid = blockIdx.x;
  const float* src;
  ushort_t* dst;
  int row;
  bool isx = false;
  if (bid < 3072)      { src = W_qkv;  dst = Wqn; row = bid; }
  else if (bid < 4096) { src = W_proj; dst = Wpn; row = bid - 3072; }
  else                 { src = x;      dst = xb;  row = bid - 4096; isx = true; }

  const float4* p = (const float4*)(src + (size_t)row * CDIM);
  int t = threadIdx.x;
  float4 a = p[t];
  float4 b = p[t + 64];
  float s = a.x * a.x + a.y * a.y + a.z * a.z + a.w * a.w
          + b.x * b.x + b.y * b.y + b.z * b.z + b.w * b.w;
#pragma unroll
  for (int off = 32; off > 0; off >>= 1) s += __shfl_down(s, off);
  s = __shfl(s, 0);
  float inv;
  if (isx) {
    if (t == 0) xs[row] = 1.0f / (sqrtf(s) * SQRT_C);
    inv = 1.0f;
  } else {
    inv = 1.0f / sqrtf(s);
  }
  short4v ya, yb;
  ya[0] = (short)f2b(a.x * inv); ya[1] = (short)f2b(a.y * inv);
  ya[2] = (short)f2b(a.z * inv); ya[3] = (short)f2b(a.w * inv);
  yb[0] = (short)f2b(b.x * inv); yb[1] = (short)f2b(b.y * inv);
  yb[2] = (short)f2b(b.z * inv); yb[3] = (short)f2b(b.w * inv);
  *(short4v*)&dst[(size_t)row * CDIM + t * 4] = ya;
  *(short4v*)&dst[(size_t)row * CDIM + 256 + t * 4] = yb;
}

// ---------------------------------------------------------------------------
// bcos GEMM, bf16 MFMA 16x16x32. 128m x (NJ*16)ch tile, BK=64 as two BK=32
// sub-stages. LDS pool (32 KB) holds staging buffers, then is reused by the
// MODE-0 epilogue as a transpose buffer for coalesced Q/K/V stores.
// MODE 0 (NJ=4): Qb [bh][n][64] (x0.125), Kt/Vt [bh][d][n]; ascale = x invnorm.
// MODE 1 (NJ=4): fp32 out; osum_p[8][4096] summed in LDS, rsqrt in epilogue.
// ---------------------------------------------------------------------------
template <int MODE, int NJ>
__global__ __launch_bounds__(256) void gemm_mfma_kernel(
    const ushort_t* __restrict__ Ab,
    const ushort_t* __restrict__ Wn,
    const float* __restrict__ ascale,
    const float* __restrict__ osum_p,
    float* __restrict__ out,
    ushort_t* __restrict__ Qb, ushort_t* __restrict__ Ktb,
    ushort_t* __restrict__ Vtb,
    int P) {
  __shared__ __align__(16) ushort_t pool[16384];   // 32 KB: At | Wt, reused by epilogue
  __shared__ float osl[128];
  const int t = threadIdx.x;
  const int lane = t & 63;
  const int w = t >> 6;
  const int mq = w & 1, wq = w >> 1;
  const int l15 = lane & 15, l4 = lane >> 4;
  const int n0 = blockIdx.x * (NJ * 16);
  const int mb = blockIdx.y * 128;

  if (MODE == 1) {
    if (t < 128) {
      float s = 0.f;
#pragma unroll
      for (int hh = 0; hh < 8; ++hh) s += osum_p[hh * TOK + mb + t];
      osl[t] = s;
    }
  }

  const int srow = lane >> 2;
  const int sch = (lane & 3) * 8;
  const int WI = NJ / 2;
  const ushort_t* ag[2];
  const ushort_t* wg[WI];
  ushort_t* al[2];
  ushort_t* wl[WI];
#pragma unroll
  for (int i = 0; i < 2; ++i) {
    int r = w * 32 + i * 16;
    ag[i] = Ab + (size_t)(mb + r + srow) * CDIM + sch;
    al[i] = pool + r * 32;
  }
#pragma unroll
  for (int i = 0; i < WI; ++i) {
    int r = w * (WI * 16) + i * 16;
    int g = r >> 4;
    int grow = n0 + (g >> 1) * 16 + srow + (g & 1) * P;
    wg[i] = Wn + (size_t)grow * CDIM + sch;
    wl[i] = pool + 8192 + r * 32;
  }

  f32x4 acc[4][NJ];
#pragma unroll
  for (int i = 0; i < 4; ++i)
#pragma unroll
    for (int j = 0; j < NJ; ++j) acc[i][j] = (f32x4){0.f, 0.f, 0.f, 0.f};

  for (int it = 0; it < 8; ++it) {
    __syncthreads();
#pragma unroll
    for (int h = 0; h < 2; ++h) {
#pragma unroll
      for (int i = 0; i < 2; ++i) gload16(ag[i] + h * 32, al[i] + h * 4096);
#pragma unroll
      for (int i = 0; i < WI; ++i) gload16(wg[i] + h * 32, wl[i] + h * (NJ * 1024));
    }
#pragma unroll
    for (int i = 0; i < 2; ++i) ag[i] += 64;
#pragma unroll
    for (int i = 0; i < WI; ++i) wg[i] += 64;
    __syncthreads();
#pragma unroll
    for (int h = 0; h < 2; ++h) {
      short8 af[4], wf[NJ];
#pragma unroll
      for (int i = 0; i < 4; ++i)
        af[i] = *(const short8*)(pool + h * 4096 + (mq * 64 + i * 16 + l15) * 32 + l4 * 8);
#pragma unroll
      for (int j = 0; j < NJ; ++j)
        wf[j] = *(const short8*)(pool + 8192 + h * (NJ * 1024) +
                                 (wq * (NJ * 16) + j * 16 + l15) * 32 + l4 * 8);
#pragma unroll
      for (int i = 0; i < 4; ++i)
#pragma unroll
        for (int j = 0; j < NJ; ++j)
          acc[i][j] = __builtin_amdgcn_mfma_f32_16x16x32_bf16(af[i], wf[j], acc[i][j], 0, 0, 0);
    }
  }

  if (MODE == 0) {
    const int which = n0 >> 9;           // block-uniform (64-ch tile = one head)
    const int h = (n0 & 511) >> 6;
    const int b = mb >> 11;
    const int bh = b * NHEADS + h;
    const int nsb = mb & 2047;
    __syncthreads();                     // staging pool now free for transpose
    if (which == 0) {
      // Q: LDS layout [n 128][dh 64] pad 72 (144 B rows, 16B aligned)
#pragma unroll
      for (int i = 0; i < 4; ++i) {
        const int ml = mq * 64 + i * 16 + l4 * 4;
        const float4 asc = *(const float4*)&ascale[mb + ml];
        const float ascv[4] = {asc.x, asc.y, asc.z, asc.w};
#pragma unroll
        for (int jt = 0; jt < 2; ++jt) {
          const int dh = (wq * 2 + jt) * 16 + l15;
          f32x4 a0 = acc[i][2 * jt], a1 = acc[i][2 * jt + 1];
#pragma unroll
          for (int r = 0; r < 4; ++r) {
            float v = fmaxf(a0[r], a1[r]);
            pool[(ml + r) * 72 + dh] = f2b(v * fabsf(v) * ascv[r] * ATTN_SCALE);
          }
        }
      }
      __syncthreads();
      ushort_t* gq = Qb + ((size_t)bh * NSEQ + nsb) * DH;
#pragma unroll
      for (int p = 0; p < 4; ++p) {
        int idx = p * 256 + t;
        int row = idx >> 3, c8 = idx & 7;
        *(short8*)(gq + row * DH + c8 * 8) = *(const short8*)(pool + row * 72 + c8 * 8);
      }
    } else {
      // K/V: LDS layout [dh 64][n 128] pad 136 (272 B rows, 16B aligned)
#pragma unroll
      for (int i = 0; i < 4; ++i) {
        const int ml = mq * 64 + i * 16 + l4 * 4;
        const float4 asc = *(const float4*)&ascale[mb + ml];
        const float ascv[4] = {asc.x, asc.y, asc.z, asc.w};
#pragma unroll
        for (int jt = 0; jt < 2; ++jt) {
          const int dh = (wq * 2 + jt) * 16 + l15;
          f32x4 a0 = acc[i][2 * jt], a1 = acc[i][2 * jt + 1];
          short4v pv;
#pragma unroll
          for (int r = 0; r < 4; ++r) {
            float v = fmaxf(a0[r], a1[r]);
            pv[r] = (short)f2b(v * fabsf(v) * ascv[r]);
          }
          *(short4v*)(pool + dh * 136 + ml) = pv;
        }
      }
      __syncthreads();
      ushort_t* gk = ((which == 1) ? Ktb : Vtb) + (size_t)bh * DH * NSEQ + nsb;
#pragma unroll
      for (int p = 0; p < 4; ++p) {
        int idx = p * 256 + t;
        int dh_r = idx >> 4, ch = idx & 15;
        *(short8*)(gk + (size_t)dh_r * NSEQ + ch * 8) =
            *(const short8*)(pool + dh_r * 136 + ch * 8);
      }
    }
  } else {
#pragma unroll
    for (int i = 0; i < 4; ++i) {
      const int ml = mq * 64 + i * 16 + l4 * 4;
      const int m = mb + ml;
      float ascv[4];
#pragma unroll
      for (int r = 0; r < 4; ++r) ascv[r] = 1.0f / (sqrtf(osl[ml + r]) * SQRT_C);
#pragma unroll
      for (int jt = 0; jt < 2; ++jt) {
        const int c = n0 + (wq * 2 + jt) * 16 + l15;
        f32x4 a0 = acc[i][2 * jt], a1 = acc[i][2 * jt + 1];
#pragma unroll
        for (int r = 0; r < 4; ++r) {
          float v = fmaxf(a0[r], a1[r]);
          out[(size_t)(m + r) * CDIM + c] = v * fabsf(v) * ascv[r];
        }
      }
    }
  }
}

// ---------------------------------------------------------------------------
// kvstat: grid (8,16) = 128 blocks. Per-slice partials, staged LDS reduce,
// zero atomics. Agp[slice][bh][66*64]: rows 0..63 M^T[dh][d], 64 ksum, 65 vsum.
// ---------------------------------------------------------------------------
__global__ __launch_bounds__(256) void kvstat_kernel(
    const ushort_t* __restrict__ Ktb,
    const ushort_t* __restrict__ Vtb,
    float* __restrict__ Agp) {
  __shared__ float Lr[2 * 66 * 66];
  const int t = threadIdx.x;
  const int lane = t & 63;
  const int w = t >> 6;
  const int l31 = lane & 31;
  const int H = lane >> 5;
  const int bh = blockIdx.y;
  const int n0 = blockIdx.x * 256 + w * 64;

  short8 onesf;
  {
    short v = (l31 == 0) ? (short)0x3F80 : (short)0;
#pragma unroll
    for (int i = 0; i < 8; ++i) onesf[i] = v;
  }

  f32x16 acc[3][3];
#pragma unroll
  for (int mt = 0; mt < 3; ++mt)
#pragma unroll
    for (int nt = 0; nt < 3; ++nt) acc[mt][nt] = fzero16();

  const ushort_t* Kbase = Ktb + (size_t)bh * DH * NSEQ;
  const ushort_t* Vbase = Vtb + (size_t)bh * DH * NSEQ;
#pragma unroll
  for (int c = 0; c < 4; ++c) {
    const int key = n0 + c * 16 + H * 8;
    short8 kf[2], vf[2];
#pragma unroll
    for (int mt = 0; mt < 2; ++mt) {
      kf[mt] = *(const short8*)(Kbase + (size_t)(mt * 32 + l31) * NSEQ + key);
      vf[mt] = *(const short8*)(Vbase + (size_t)(mt * 32 + l31) * NSEQ + key);
    }
#pragma unroll
    for (int mt = 0; mt < 3; ++mt) {
      short8 a = (mt < 2) ? kf[mt] : onesf;
#pragma unroll
      for (int nt = 0; nt < 3; ++nt) {
        if (mt == 2 && nt == 2) continue;
        short8 bfr = (nt < 2) ? vf[nt] : onesf;
        acc[mt][nt] = __builtin_amdgcn_mfma_f32_32x32x16_bf16(a, bfr, acc[mt][nt], 0, 0, 0);
      }
    }
  }

  float* D = Lr + (w & 1) * (66 * 66);
  if (w < 2) {
#pragma unroll
    for (int mt = 0; mt < 3; ++mt)
#pragma unroll
      for (int nt = 0; nt < 3; ++nt) {
        if (mt == 2 && nt == 2) continue;
#pragma unroll
        for (int r = 0; r < 16; ++r) {
          int rloc = (r & 3) + 8 * (r >> 2) + 4 * H;
          int row = (mt < 2) ? mt * 32 + rloc : 64;
          int col = (nt < 2) ? nt * 32 + l31 : 64;
          bool valid = (mt < 2 || rloc == 0) && (nt < 2 || l31 == 0);
          if (valid) D[row * 66 + col] = acc[mt][nt][r];
        }
      }
  }
  __syncthreads();
  if (w >= 2) {
#pragma unroll
    for (int mt = 0; mt < 3; ++mt)
#pragma unroll
      for (int nt = 0; nt < 3; ++nt) {
        if (mt == 2 && nt == 2) continue;
#pragma unroll
        for (int r = 0; r < 16; ++r) {
          int rloc = (r & 3) + 8 * (r >> 2) + 4 * H;
          int row = (mt < 2) ? mt * 32 + rloc : 64;
          int col = (nt < 2) ? nt * 32 + l31 : 64;
          bool valid = (mt < 2 || rloc == 0) && (nt < 2 || l31 == 0);
          if (valid) D[row * 66 + col] += acc[mt][nt][r];
        }
      }
  }
  __syncthreads();

  float* ag = Agp + ((size_t)blockIdx.x * NBH + bh) * (66 * 64);
  const float* L0 = Lr;
  const float* L1 = Lr + 66 * 66;
  for (int e = t; e < 66 * 64; e += 256) {
    int j = e >> 6, i = e & 63;
    int idx = (j < 64) ? i * 66 + j : (j == 64 ? i * 66 + 64 : 64 * 66 + i);
    ag[e] = L0[idx] + L1[idx];
  }
}

// ---------------------------------------------------------------------------
// attn_apply: attn = (vsum + q~.M)/(2048 + q~.ksum); sums 8 partial slices.
// Writes bf16 attn + per-head osum partials (non-atomic).
// ---------------------------------------------------------------------------
__global__ __launch_bounds__(256) void attn_apply_kernel(
    const ushort_t* __restrict__ Qb,
    const float* __restrict__ Agp,
    ushort_t* __restrict__ attnb,
    float* __restrict__ osum_p) {      // [8][4096]
  __shared__ ushort_t Bs[96 * 72];
  __shared__ float vs_lds[64];
  const int t = threadIdx.x;
  const int lane = t & 63;
  const int w = t >> 6;
  const int l31 = lane & 31;
  const int H = lane >> 5;
  const int bh = blockIdx.y;
  const int tok0 = blockIdx.x * 128 + w * 32;

  const float* agp = Agp + (size_t)bh * (66 * 64);
  const size_t sstr = (size_t)NBH * 66 * 64;
  for (int e = t; e < 64 * 64; e += 256) {
    float s = 0.f;
#pragma unroll
    for (int sl = 0; sl < 8; ++sl) s += agp[sl * sstr + e];
    Bs[(e >> 6) * 72 + (e & 63)] = f2b(s);
  }
  for (int e = t; e < 32 * 64; e += 256) {
    int j = e >> 6, i = e & 63;
    ushort_t v = 0;
    if (j == 0) {
      float s = 0.f;
#pragma unroll
      for (int sl = 0; sl < 8; ++sl) s += agp[sl * sstr + 64 * 64 + i];
      v = f2b(s);
    }
    Bs[(64 + j) * 72 + i] = v;
  }
  if (t < 64) {
    float s = 0.f;
#pragma unroll
    for (int sl = 0; sl < 8; ++sl) s += agp[sl * sstr + 65 * 64 + t];
    vs_lds[t] = s;
  }
  __syncthreads();

  short8 qf[4];
  {
    const ushort_t* qp = Qb + ((size_t)bh * NSEQ + tok0 + l31) * DH + H * 8;
#pragma unroll
    for (int c = 0; c < 4; ++c) qf[c] = *(const short8*)(qp + c * 16);
  }

  f32x16 oacc[3];
#pragma unroll
  for (int nt = 0; nt < 3; ++nt) oacc[nt] = fzero16();
#pragma unroll
  for (int c = 0; c < 4; ++c) {
#pragma unroll
    for (int nt = 0; nt < 3; ++nt) {
      short8 bfr = *(const short8*)(Bs + (nt * 32 + l31) * 72 + c * 16 + H * 8);
      oacc[nt] = __builtin_amdgcn_mfma_f32_32x32x16_bf16(qf[c], bfr, oacc[nt], 0, 0, 0);
    }
  }

  const int b = bh >> 3, h = bh & 7;
#pragma unroll
  for (int r = 0; r < 16; ++r) {
    int rloc = (r & 3) + 8 * (r >> 2) + 4 * H;
    float den = 2048.0f + __shfl(oacc[2][r], H * 32);
    float inv = 1.0f / den;
    float v0 = (vs_lds[l31] + oacc[0][r]) * inv;
    float v1 = (vs_lds[32 + l31] + oacc[1][r]) * inv;
    int n = tok0 + rloc;
    ushort_t* op = attnb + ((size_t)(b * NSEQ + n)) * CDIM + h * DH;
    op[l31] = f2b(v0);
    op[32 + l31] = f2b(v1);
    float ss = v0 * v0 + v1 * v1;
#pragma unroll
    for (int off = 16; off > 0; off >>= 1) ss += __shfl_down(ss, off, 32);
    if (l31 == 0) osum_p[h * TOK + b * NSEQ + n] = ss;
  }
}

extern "C" void kernel_launch(void* const* d_in, const int* in_sizes, int n_in,
                              void* d_out, int out_size, void* d_ws, size_t ws_size,
                              hipStream_t stream) {
  const float* x      = (const float*)d_in[0];
  const float* W_qkv  = (const float*)d_in[1];
  const float* W_proj = (const float*)d_in[2];
  float* out = (float*)d_out;

  char* wsb = (char*)d_ws;
  ushort_t* Wqn = (ushort_t*)(wsb + 0);          // 3072x512 bf16
  ushort_t* Wpn = (ushort_t*)(wsb + 3145728);    // 1024x512 bf16
  ushort_t* xb  = (ushort_t*)(wsb + 4194304);    // 4096x512 bf16; reused as attnb
  ushort_t* Qb  = (ushort_t*)(wsb + 8388608);    // [bh][n][64] bf16
  ushort_t* Ktb = (ushort_t*)(wsb + 12582912);   // [bh][d][n] bf16
  ushort_t* Vtb = (ushort_t*)(wsb + 16777216);   // [bh][dh][n] bf16
  float* xs     = (float*)(wsb + 20971520);      // 4096
  float* osum_p = (float*)(wsb + 20987904);      // 8 x 4096
  float* Agp    = (float*)(wsb + 21118976);      // 8 x 16 x 66*64

  prep_kernel<<<8192, 64, 0, stream>>>(W_qkv, W_proj, x, Wqn, Wpn, xb, xs);

  gemm_mfma_kernel<0, 4><<<dim3(1536 / 64, TOK / 128), 256, 0, stream>>>(
      xb, Wqn, xs, nullptr, nullptr, Qb, Ktb, Vtb, 1536);

  kvstat_kernel<<<dim3(8, NBH), 256, 0, stream>>>(Ktb, Vtb, Agp);

  attn_apply_kernel<<<dim3(16, NBH), 256, 0, stream>>>(Qb, Agp, xb, osum_p);

  gemm_mfma_kernel<1, 4><<<dim3(512 / 64, TOK / 128), 256, 0, stream>>>(
      xb, Wpn, nullptr, osum_p, out, nullptr, nullptr, nullptr, 512);
}